// Round 8
// baseline (239.935 us; speedup 1.0000x reference)
//
#include <hip/hip_runtime.h>
#include <math.h>

#define B_   8
#define L_   512
#define DIN  1024
#define H_   128
#define HEAD 64
#define NL   16
#define INF_ 1.0e12f

// ws layout (float offsets)
#define SIN_OFF  0
#define COS_OFF  (512*32)
#define QROT_OFF (COS_OFF + 512*32)            // 32768
#define KROT_OFF (QROT_OFF + B_*L_*HEAD)
#define BQ_OFF   (KROT_OFF + B_*L_*HEAD)       // odd channels -> added along m
#define BK_OFF   (BQ_OFF + B_*NL*L_)           // even channels -> added along n
#define W1T_OFF  (BK_OFF + B_*NL*L_)           // bf16 [n=128][k=1024] = 65536 floats
#define W2T_OFF  (W1T_OFF + 65536)             // bf16 [o=32][k=128]  = 2048 floats

#define XS_STRIDE 1028   // 1024 + 4 floats pad

// DIAGNOSTIC ROUND 2: surface prep and gemm1 in rocprof top-5 with counters.
#define PREP_REPS  48
#define GEMM1_REPS 16

typedef float          floatx4  __attribute__((ext_vector_type(4)));
typedef short          shortx8  __attribute__((ext_vector_type(8)));
typedef unsigned short ushortx8 __attribute__((ext_vector_type(8)));

__device__ __forceinline__ unsigned short f2bf(float f) {
    unsigned u = __float_as_uint(f);
    u += 0x7FFFu + ((u >> 16) & 1u);   // RNE
    return (unsigned short)(u >> 16);
}

// --------------------------------------------------------------------------
// prep: blocks 0..63 rope table (f32); 64..79 W1->W1T bf16; 80 W2->W2T bf16
__global__ __launch_bounds__(256) void prep_kernel(const float* __restrict__ W1,
                                                   const float* __restrict__ W2,
                                                   float* __restrict__ ws) {
    __shared__ float lds[64 * 132];
    const int tid = threadIdx.x;
    const int bid = blockIdx.x;

    #pragma unroll 1
    for (int rep = 0; rep < PREP_REPS; rep++) {
        __syncthreads();
        if (bid < 64) {
            int idx = bid * 256 + tid;
            int m = idx >> 5, i = idx & 31;
            float freq = expf(-(float)i * 0.28782313662425575f);
            float ang  = (float)m * freq;
            ws[SIN_OFF + idx] = sinf(ang);
            ws[COS_OFF + idx] = cosf(ang);
        } else if (bid < 80) {
            const int k0 = (bid - 64) * 64;
            for (int i = 0; i < 8; i++) {
                int f = tid + i * 256;              // float4 index over 2048
                int k = f >> 5, n4 = (f & 31) * 4;
                *(float4*)&lds[k * 132 + n4] = *(const float4*)&W1[(size_t)(k0 + k) * H_ + n4];
            }
            __syncthreads();
            unsigned short* W1T = (unsigned short*)(ws + W1T_OFF);
            const int n  = tid >> 1;
            const int kh = (tid & 1) * 32;
            for (int i = 0; i < 4; i++) {
                ushortx8 p;
                #pragma unroll
                for (int j = 0; j < 8; j++) p[j] = f2bf(lds[(kh + i * 8 + j) * 132 + n]);
                *(ushortx8*)&W1T[(size_t)n * DIN + k0 + kh + i * 8] = p;
            }
        } else {
            // W2 [128][32] -> W2T bf16 [32][128]
            unsigned short* W2T = (unsigned short*)(ws + W2T_OFF);
            const int o  = tid >> 3;          // 0..31
            const int kc = (tid & 7) * 16;    // 0..112
            ushortx8 p0, p1;
            #pragma unroll
            for (int j = 0; j < 8; j++) p0[j] = f2bf(W2[(size_t)(kc + j) * 32 + o]);
            #pragma unroll
            for (int j = 0; j < 8; j++) p1[j] = f2bf(W2[(size_t)(kc + 8 + j) * 32 + o]);
            *(ushortx8*)&W2T[(size_t)o * H_ + kc]     = p0;
            *(ushortx8*)&W2T[(size_t)o * H_ + kc + 8] = p1;
        }
    }
}

// --------------------------------------------------------------------------
// K2: h = X@W1 + b1 via bf16 MFMA, split-K x4 (16 waves/block), X staged to
// LDS coalesced. rep'd x16 for diagnostics.
__global__ __launch_bounds__(1024, 4) void gemm1_fused_kernel(
    const float* __restrict__ X, const float* __restrict__ b1,
    const float* __restrict__ b2, float* __restrict__ ws)
{
    __shared__ float Xs[16 * XS_STRIDE];       // 65792 B; reused as red[] later
    __shared__ float hs[16 * 132];

    float (*red)[16][64] = (float(*)[16][64])Xs;   // overlay (after barrier)

    const int tid  = threadIdx.x;
    const int m0   = blockIdx.x * 16;
    const int w    = tid >> 6;
    const int g    = w & 3;            // n-group
    const int s    = w >> 2;           // k-split
    const int lane = tid & 63;
    const int lrow = lane >> 4;        // 0..3
    const int lcol = lane & 15;        // 0..15

    const unsigned short* W1T = (const unsigned short*)(ws + W1T_OFF);

    #pragma unroll 1
    for (int rep = 0; rep < GEMM1_REPS; rep++) {
        __syncthreads();

        // ---- stage X tile: wave w stages row w, 4 contiguous 1KB sweeps ----
        {
            const float* xrow = X + (size_t)(m0 + w) * DIN;
            float4 v0 = *(const float4*)(xrow + 0 * 256 + lane * 4);
            float4 v1 = *(const float4*)(xrow + 1 * 256 + lane * 4);
            float4 v2 = *(const float4*)(xrow + 2 * 256 + lane * 4);
            float4 v3 = *(const float4*)(xrow + 3 * 256 + lane * 4);
            float* drow = &Xs[w * XS_STRIDE];
            *(float4*)(drow + 0 * 256 + lane * 4) = v0;
            *(float4*)(drow + 1 * 256 + lane * 4) = v1;
            *(float4*)(drow + 2 * 256 + lane * 4) = v2;
            *(float4*)(drow + 3 * 256 + lane * 4) = v3;
        }
        __syncthreads();

        // ---- K-loop: A fragments from LDS, B fragments from global ----
        const float* pA = &Xs[lcol * XS_STRIDE + s * 256 + lrow * 8];
        const unsigned short* pB0 = W1T + (size_t)(g * 32 + lcol) * DIN + s * 256 + lrow * 8;
        const unsigned short* pB1 = pB0 + (size_t)16 * DIN;

        floatx4 acc0 = {0.f, 0.f, 0.f, 0.f};
        floatx4 acc1 = {0.f, 0.f, 0.f, 0.f};

        #pragma unroll
        for (int st = 0; st < 8; st++) {
            float4 a0 = *(const float4*)(pA + st * 32);
            float4 a1 = *(const float4*)(pA + st * 32 + 4);
            shortx8 bf0 = *(const shortx8*)(pB0 + st * 32);
            shortx8 bf1 = *(const shortx8*)(pB1 + st * 32);
            ushortx8 afu;
            afu[0] = f2bf(a0.x); afu[1] = f2bf(a0.y); afu[2] = f2bf(a0.z); afu[3] = f2bf(a0.w);
            afu[4] = f2bf(a1.x); afu[5] = f2bf(a1.y); afu[6] = f2bf(a1.z); afu[7] = f2bf(a1.w);
            shortx8 af = (shortx8)afu;
            acc0 = __builtin_amdgcn_mfma_f32_16x16x32_bf16(af, bf0, acc0, 0, 0, 0);
            acc1 = __builtin_amdgcn_mfma_f32_16x16x32_bf16(af, bf1, acc1, 0, 0, 0);
        }
        __syncthreads();   // Xs reads done -> safe to overlay red[]

        // write partials
        #pragma unroll
        for (int r = 0; r < 4; r++) {
            red[r][w][lane]     = acc0[r];
            red[4 + r][w][lane] = acc1[r];
        }
        __syncthreads();

        // waves 0..3: reduce 4 k-splits, +b1, park in hs.
        if (w < 4) {
            float b1a = b1[g * 32 + lcol];
            float b1b = b1[g * 32 + 16 + lcol];
            #pragma unroll
            for (int r = 0; r < 4; r++) {
                float v0 = red[r][g][lane]     + red[r][g + 4][lane]
                         + red[r][g + 8][lane] + red[r][g + 12][lane];
                float v1 = red[4 + r][g][lane]     + red[4 + r][g + 4][lane]
                         + red[4 + r][g + 8][lane] + red[4 + r][g + 12][lane];
                hs[(lrow * 4 + r) * 132 + g * 32 + lcol]      = v0 + b1a;
                hs[(lrow * 4 + r) * 132 + g * 32 + 16 + lcol] = v1 + b1b;
            }
        }
        __syncthreads();

        // rotary: threads 0..255
        if (tid < 256) {
            int row = tid >> 4;
            int j   = tid & 15;
            int gg  = m0 + row;
            int pos = gg & (L_ - 1);
            const float* hr = &hs[row * 132];
            float h0 = hr[8 * j + 0], h1 = hr[8 * j + 1];
            float h2 = hr[8 * j + 2], h3 = hr[8 * j + 3];
            float h4 = hr[8 * j + 4], h5 = hr[8 * j + 5];
            float h6 = hr[8 * j + 6], h7 = hr[8 * j + 7];
            float s0 = ws[SIN_OFF + pos * 32 + 2 * j];
            float c0 = ws[COS_OFF + pos * 32 + 2 * j];
            float s1 = ws[SIN_OFF + pos * 32 + 2 * j + 1];
            float c1 = ws[COS_OFF + pos * 32 + 2 * j + 1];
            float4 q, k;
            q.x = h0 * c0 - h2 * s0;  q.y = h2 * c0 + h0 * s0;
            q.z = h4 * c1 - h6 * s1;  q.w = h6 * c1 + h4 * s1;
            k.x = h1 * c0 - h3 * s0;  k.y = h3 * c0 + h1 * s0;
            k.z = h5 * c1 - h7 * s1;  k.w = h7 * c1 + h5 * s1;
            *(float4*)&ws[QROT_OFF + (size_t)gg * HEAD + 4 * j] = q;
            *(float4*)&ws[KROT_OFF + (size_t)gg * HEAD + 4 * j] = k;
        }

        // bias = (h @ W2 + b2) * 0.5 via MFMA on wave 0
        if (w == 0) {
            const unsigned short* W2T = (const unsigned short*)(ws + W2T_OFF);
            floatx4 bacc0 = {0.f, 0.f, 0.f, 0.f};
            floatx4 bacc1 = {0.f, 0.f, 0.f, 0.f};
            #pragma unroll
            for (int st = 0; st < 4; st++) {
                int k = st * 32 + lrow * 8;
                ushortx8 hfu;
                #pragma unroll
                for (int j = 0; j < 8; j++) hfu[j] = f2bf(hs[lcol * 132 + k + j]);
                shortx8 hf = (shortx8)hfu;
                shortx8 wf0 = *(const shortx8*)(W2T + (size_t)lcol * H_ + k);
                shortx8 wf1 = *(const shortx8*)(W2T + (size_t)(16 + lcol) * H_ + k);
                bacc0 = __builtin_amdgcn_mfma_f32_16x16x32_bf16(hf, wf0, bacc0, 0, 0, 0);
                bacc1 = __builtin_amdgcn_mfma_f32_16x16x32_bf16(hf, wf1, bacc1, 0, 0, 0);
            }
            float b2a = b2[lcol], b2b = b2[16 + lcol];
            #pragma unroll
            for (int r = 0; r < 4; r++) {
                int gg  = m0 + lrow * 4 + r;
                int bb  = gg >> 9;
                int pos = gg & (L_ - 1);
                float v0 = (bacc0[r] + b2a) * 0.5f;
                float v1 = (bacc1[r] + b2b) * 0.5f;
                int o0 = lcol, o1 = 16 + lcol;
                if (o0 & 1) ws[BQ_OFF + ((size_t)bb * NL + (o0 >> 1)) * L_ + pos] = v0;
                else        ws[BK_OFF + ((size_t)bb * NL + (o0 >> 1)) * L_ + pos] = v0;
                if (o1 & 1) ws[BQ_OFF + ((size_t)bb * NL + (o1 >> 1)) * L_ + pos] = v1;
                else        ws[BK_OFF + ((size_t)bb * NL + (o1 >> 1)) * L_ + pos] = v1;
            }
        }
    }
}

// --------------------------------------------------------------------------
// K3 (fused): qk 64x64 tile in registers -> +bias/masks -> 16 l stores.
__global__ __launch_bounds__(256) void qk_bcast_kernel(
    const int* __restrict__ am, const float* __restrict__ ws, float* __restrict__ out)
{
    __shared__ float Qs[64][68];
    __shared__ float Ks[64][68];
    __shared__ float BQs[16][64];
    __shared__ float BKs[16][64];
    __shared__ float maskM[64];
    __shared__ float maskN[64];

    const int tid = threadIdx.x;
    const int bid = blockIdx.x;
    const int bb = bid >> 6;
    const int mt = (bid >> 3) & 7;
    const int nt = bid & 7;
    const int m0 = mt * 64, n0 = nt * 64;

    // stage Q/K transposed
    {
        int r0   = tid >> 4;
        int dcol = (tid & 15) * 4;
        #pragma unroll
        for (int rr = 0; rr < 4; rr++) {
            int r = r0 + rr * 16;
            float4 q = *(const float4*)&ws[QROT_OFF + ((size_t)(bb * L_ + m0 + r)) * HEAD + dcol];
            float4 k = *(const float4*)&ws[KROT_OFF + ((size_t)(bb * L_ + n0 + r)) * HEAD + dcol];
            Qs[dcol + 0][r] = q.x; Qs[dcol + 1][r] = q.y;
            Qs[dcol + 2][r] = q.z; Qs[dcol + 3][r] = q.w;
            Ks[dcol + 0][r] = k.x; Ks[dcol + 1][r] = k.y;
            Ks[dcol + 2][r] = k.z; Ks[dcol + 3][r] = k.w;
        }
    }
    // stage BQ/BK tiles: 16 l x 64
    {
        int l = tid >> 4;
        int c = (tid & 15) * 4;
        *(float4*)&BQs[l][c] = *(const float4*)&ws[BQ_OFF + ((size_t)bb * NL + l) * L_ + m0 + c];
        *(float4*)&BKs[l][c] = *(const float4*)&ws[BK_OFF + ((size_t)bb * NL + l) * L_ + n0 + c];
    }
    if (tid < 64)       maskM[tid]      = (float)am[bb * L_ + m0 + tid];
    else if (tid < 128) maskN[tid - 64] = (float)am[bb * L_ + n0 + (tid - 64)];
    __syncthreads();

    const int ty = tid >> 4;
    const int tx = tid & 15;
    float acc[4][4] = {};
    #pragma unroll 8
    for (int d = 0; d < HEAD; d++) {
        float4 a  = *(const float4*)&Qs[d][ty * 4];
        float4 bv = *(const float4*)&Ks[d][tx * 4];
        acc[0][0] += a.x * bv.x; acc[0][1] += a.x * bv.y; acc[0][2] += a.x * bv.z; acc[0][3] += a.x * bv.w;
        acc[1][0] += a.y * bv.x; acc[1][1] += a.y * bv.y; acc[1][2] += a.y * bv.z; acc[1][3] += a.y * bv.w;
        acc[2][0] += a.z * bv.x; acc[2][1] += a.z * bv.y; acc[2][2] += a.z * bv.z; acc[2][3] += a.z * bv.w;
        acc[3][0] += a.w * bv.x; acc[3][1] += a.w * bv.y; acc[3][2] += a.w * bv.z; acc[3][3] += a.w * bv.w;
    }

    // base = qk*0.125 - attn_mask*INF - tril*INF
    float4 base[4];
    #pragma unroll
    for (int r = 0; r < 4; r++) {
        int m = m0 + ty * 4 + r;
        float mm = maskM[ty * 4 + r];
        #pragma unroll
        for (int c = 0; c < 4; c++) {
            int n = n0 + tx * 4 + c;
            float v = acc[r][c] * 0.125f
                    - (1.0f - mm * maskN[tx * 4 + c]) * INF_
                    - ((n < m) ? INF_ : 0.0f);
            ((float*)&base[r])[c] = v;
        }
    }

    // output: 16 l-channels x 4 rows x float4
    #pragma unroll
    for (int l = 0; l < NL; l++) {
        float4 bk4 = *(const float4*)&BKs[l][tx * 4];
        size_t outb = (((size_t)(bb * NL + l)) * L_ + m0 + ty * 4) * L_ + n0 + tx * 4;
        #pragma unroll
        for (int r = 0; r < 4; r++) {
            float bq = BQs[l][ty * 4 + r];
            float4 o;
            o.x = base[r].x + bk4.x + bq;
            o.y = base[r].y + bk4.y + bq;
            o.z = base[r].z + bk4.z + bq;
            o.w = base[r].w + bk4.w + bq;
            *(float4*)&out[outb + (size_t)r * L_] = o;
        }
    }
}

// --------------------------------------------------------------------------
extern "C" void kernel_launch(void* const* d_in, const int* in_sizes, int n_in,
                              void* d_out, int out_size, void* d_ws, size_t ws_size,
                              hipStream_t stream) {
    const float* X  = (const float*)d_in[0];
    const int*   am = (const int*)d_in[1];
    const float* W1 = (const float*)d_in[2];
    const float* b1 = (const float*)d_in[3];
    const float* W2 = (const float*)d_in[4];
    const float* b2 = (const float*)d_in[5];
    float* out = (float*)d_out;
    float* ws  = (float*)d_ws;

    prep_kernel<<<81, 256, 0, stream>>>(W1, W2, ws);
    gemm1_fused_kernel<<<(B_ * L_) / 16, 1024, 0, stream>>>(X, b1, b2, ws);
    qk_bcast_kernel<<<B_ * (L_ / 64) * (L_ / 64), 256, 0, stream>>>(am, ws, out);
}

// Round 9
// 48.482 us; speedup vs baseline: 4.9489x; 4.9489x over previous
//
#include <hip/hip_runtime.h>
#include <math.h>

#define B_   8
#define L_   512
#define DIN  1024
#define H_   128
#define HEAD 64
#define NL   16
#define INF_ 1.0e12f

// ws layout (float offsets)
#define SIN_OFF  0
#define COS_OFF  (512*32)
#define QROT_OFF (COS_OFF + 512*32)            // 32768
#define KROT_OFF (QROT_OFF + B_*L_*HEAD)
#define BQ_OFF   (KROT_OFF + B_*L_*HEAD)       // odd channels -> added along m
#define BK_OFF   (BQ_OFF + B_*NL*L_)           // even channels -> added along n
#define W1T_OFF  (BK_OFF + B_*NL*L_)           // bf16 [n=128][k=1024] = 65536 floats
#define W2T_OFF  (W1T_OFF + 65536)             // bf16 [o=32][k=128]  = 2048 floats

#define XSH_STRIDE 1032   // shorts per row: 1024 + 8 pad

typedef float          floatx4  __attribute__((ext_vector_type(4)));
typedef short          shortx8  __attribute__((ext_vector_type(8)));
typedef unsigned short ushortx8 __attribute__((ext_vector_type(8)));

__device__ __forceinline__ unsigned short f2bf(float f) {
    unsigned u = __float_as_uint(f);
    u += 0x7FFFu + ((u >> 16) & 1u);   // RNE
    return (unsigned short)(u >> 16);
}

// --------------------------------------------------------------------------
// prep: blocks 0..63 rope table (f32); 64..79 W1->W1T bf16; 80 W2->W2T bf16
__global__ __launch_bounds__(256) void prep_kernel(const float* __restrict__ W1,
                                                   const float* __restrict__ W2,
                                                   float* __restrict__ ws) {
    __shared__ float lds[64 * 132];
    const int tid = threadIdx.x;
    const int bid = blockIdx.x;

    if (bid < 64) {
        int idx = bid * 256 + tid;
        int m = idx >> 5, i = idx & 31;
        float freq = expf(-(float)i * 0.28782313662425575f);
        float ang  = (float)m * freq;
        ws[SIN_OFF + idx] = sinf(ang);
        ws[COS_OFF + idx] = cosf(ang);
    } else if (bid < 80) {
        const int k0 = (bid - 64) * 64;
        for (int i = 0; i < 8; i++) {
            int f = tid + i * 256;              // float4 index over 2048
            int k = f >> 5, n4 = (f & 31) * 4;
            *(float4*)&lds[k * 132 + n4] = *(const float4*)&W1[(size_t)(k0 + k) * H_ + n4];
        }
        __syncthreads();
        unsigned short* W1T = (unsigned short*)(ws + W1T_OFF);
        const int n  = tid >> 1;
        const int kh = (tid & 1) * 32;
        for (int i = 0; i < 4; i++) {
            ushortx8 p;
            #pragma unroll
            for (int j = 0; j < 8; j++) p[j] = f2bf(lds[(kh + i * 8 + j) * 132 + n]);
            *(ushortx8*)&W1T[(size_t)n * DIN + k0 + kh + i * 8] = p;
        }
    } else {
        // W2 [128][32] -> W2T bf16 [32][128]
        unsigned short* W2T = (unsigned short*)(ws + W2T_OFF);
        const int o  = tid >> 3;          // 0..31
        const int kc = (tid & 7) * 16;    // 0..112
        ushortx8 p0, p1;
        #pragma unroll
        for (int j = 0; j < 8; j++) p0[j] = f2bf(W2[(size_t)(kc + j) * 32 + o]);
        #pragma unroll
        for (int j = 0; j < 8; j++) p1[j] = f2bf(W2[(size_t)(kc + 8 + j) * 32 + o]);
        *(ushortx8*)&W2T[(size_t)o * H_ + kc]     = p0;
        *(ushortx8*)&W2T[(size_t)o * H_ + kc + 8] = p1;
    }
}

// --------------------------------------------------------------------------
// K2: h = X@W1 + b1 via bf16 MFMA, split-K x4 (16 waves/block).
// All 16 B-fragments hoisted into registers (issued with X loads up front);
// X staged to LDS as bf16 (cvt once); K-loop = 8x{ds_read_b128, 2 MFMA}.
__global__ __launch_bounds__(1024, 2) void gemm1_fused_kernel(
    const float* __restrict__ X, const float* __restrict__ b1,
    const float* __restrict__ b2, float* __restrict__ ws)
{
    __shared__ __align__(16) float shbuf[8256];   // Xsh bf16[16][1032] / red[8][16][64]
    __shared__ float hs[16 * 132];

    unsigned short* Xsh = (unsigned short*)shbuf;
    float (*red)[16][64] = (float(*)[16][64])shbuf;

    const int tid  = threadIdx.x;
    const int m0   = blockIdx.x * 16;
    const int w    = tid >> 6;
    const int g    = w & 3;            // n-group
    const int s    = w >> 2;           // k-split
    const int lane = tid & 63;
    const int lrow = lane >> 4;        // 0..3
    const int lcol = lane & 15;        // 0..15

    const unsigned short* W1T = (const unsigned short*)(ws + W1T_OFF);

    // ---- issue X loads (HBM, longest latency) ----
    const float* xrow = X + (size_t)(m0 + w) * DIN + lane * 8;
    float4 x0 = *(const float4*)(xrow + 0);
    float4 x1 = *(const float4*)(xrow + 4);
    float4 x2 = *(const float4*)(xrow + 512);
    float4 x3 = *(const float4*)(xrow + 516);

    // ---- issue ALL 16 B-fragment loads (L2-resident W1T) ----
    const unsigned short* pB0 = W1T + (size_t)(g * 32 + lcol) * DIN + s * 256 + lrow * 8;
    const unsigned short* pB1 = pB0 + (size_t)16 * DIN;
    shortx8 bfr[16];
    #pragma unroll
    for (int st = 0; st < 8; st++) {
        bfr[2 * st]     = *(const shortx8*)(pB0 + st * 32);
        bfr[2 * st + 1] = *(const shortx8*)(pB1 + st * 32);
    }

    // ---- cvt X -> bf16, stage to LDS (conflict-free contiguous b128) ----
    {
        ushortx8 ua, ub;
        ua[0] = f2bf(x0.x); ua[1] = f2bf(x0.y); ua[2] = f2bf(x0.z); ua[3] = f2bf(x0.w);
        ua[4] = f2bf(x1.x); ua[5] = f2bf(x1.y); ua[6] = f2bf(x1.z); ua[7] = f2bf(x1.w);
        ub[0] = f2bf(x2.x); ub[1] = f2bf(x2.y); ub[2] = f2bf(x2.z); ub[3] = f2bf(x2.w);
        ub[4] = f2bf(x3.x); ub[5] = f2bf(x3.y); ub[6] = f2bf(x3.z); ub[7] = f2bf(x3.w);
        *(ushortx8*)&Xsh[w * XSH_STRIDE + lane * 8]       = ua;
        *(ushortx8*)&Xsh[w * XSH_STRIDE + 512 + lane * 8] = ub;
    }
    __syncthreads();

    // ---- K-loop: A frags from LDS (bf16), B frags already in registers ----
    const unsigned short* pA = &Xsh[lcol * XSH_STRIDE + s * 256 + lrow * 8];

    floatx4 acc0 = {0.f, 0.f, 0.f, 0.f};
    floatx4 acc1 = {0.f, 0.f, 0.f, 0.f};

    #pragma unroll
    for (int st = 0; st < 8; st++) {
        shortx8 af = *(const shortx8*)(pA + st * 32);
        acc0 = __builtin_amdgcn_mfma_f32_16x16x32_bf16(af, bfr[2 * st],     acc0, 0, 0, 0);
        acc1 = __builtin_amdgcn_mfma_f32_16x16x32_bf16(af, bfr[2 * st + 1], acc1, 0, 0, 0);
    }
    __syncthreads();   // Xsh reads done -> safe to overlay red[]

    // write partials
    #pragma unroll
    for (int r = 0; r < 4; r++) {
        red[r][w][lane]     = acc0[r];
        red[4 + r][w][lane] = acc1[r];
    }
    __syncthreads();

    // waves 0..3: reduce 4 k-splits, +b1, park in hs.
    // C layout: col=lane&15, row=(lane>>4)*4+r  [m89]
    if (w < 4) {
        float b1a = b1[g * 32 + lcol];
        float b1b = b1[g * 32 + 16 + lcol];
        #pragma unroll
        for (int r = 0; r < 4; r++) {
            float v0 = red[r][g][lane]     + red[r][g + 4][lane]
                     + red[r][g + 8][lane] + red[r][g + 12][lane];
            float v1 = red[4 + r][g][lane]     + red[4 + r][g + 4][lane]
                     + red[4 + r][g + 8][lane] + red[4 + r][g + 12][lane];
            hs[(lrow * 4 + r) * 132 + g * 32 + lcol]      = v0 + b1a;
            hs[(lrow * 4 + r) * 132 + g * 32 + 16 + lcol] = v1 + b1b;
        }
    }
    __syncthreads();

    // rotary: threads 0..255 -> (row 0..15, j 0..15); outputs d = 4j..4j+3
    if (tid < 256) {
        int row = tid >> 4;
        int j   = tid & 15;
        int gg  = m0 + row;
        int pos = gg & (L_ - 1);
        const float* hr = &hs[row * 132];
        float h0 = hr[8 * j + 0], h1 = hr[8 * j + 1];
        float h2 = hr[8 * j + 2], h3 = hr[8 * j + 3];
        float h4 = hr[8 * j + 4], h5 = hr[8 * j + 5];
        float h6 = hr[8 * j + 6], h7 = hr[8 * j + 7];
        float s0 = ws[SIN_OFF + pos * 32 + 2 * j];
        float c0 = ws[COS_OFF + pos * 32 + 2 * j];
        float s1 = ws[SIN_OFF + pos * 32 + 2 * j + 1];
        float c1 = ws[COS_OFF + pos * 32 + 2 * j + 1];
        float4 q, k;
        q.x = h0 * c0 - h2 * s0;  q.y = h2 * c0 + h0 * s0;
        q.z = h4 * c1 - h6 * s1;  q.w = h6 * c1 + h4 * s1;
        k.x = h1 * c0 - h3 * s0;  k.y = h3 * c0 + h1 * s0;
        k.z = h5 * c1 - h7 * s1;  k.w = h7 * c1 + h5 * s1;
        *(float4*)&ws[QROT_OFF + (size_t)gg * HEAD + 4 * j] = q;
        *(float4*)&ws[KROT_OFF + (size_t)gg * HEAD + 4 * j] = k;
    }

    // bias = (h @ W2 + b2) * 0.5 via MFMA on wave 0: M=16, N=32 (2 tiles), K=128
    if (w == 0) {
        const unsigned short* W2T = (const unsigned short*)(ws + W2T_OFF);
        floatx4 bacc0 = {0.f, 0.f, 0.f, 0.f};
        floatx4 bacc1 = {0.f, 0.f, 0.f, 0.f};
        #pragma unroll
        for (int st = 0; st < 4; st++) {
            int k = st * 32 + lrow * 8;
            ushortx8 hfu;
            #pragma unroll
            for (int j = 0; j < 8; j++) hfu[j] = f2bf(hs[lcol * 132 + k + j]);
            shortx8 hf = (shortx8)hfu;
            shortx8 wf0 = *(const shortx8*)(W2T + (size_t)lcol * H_ + k);
            shortx8 wf1 = *(const shortx8*)(W2T + (size_t)(16 + lcol) * H_ + k);
            bacc0 = __builtin_amdgcn_mfma_f32_16x16x32_bf16(hf, wf0, bacc0, 0, 0, 0);
            bacc1 = __builtin_amdgcn_mfma_f32_16x16x32_bf16(hf, wf1, bacc1, 0, 0, 0);
        }
        float b2a = b2[lcol], b2b = b2[16 + lcol];
        #pragma unroll
        for (int r = 0; r < 4; r++) {
            int gg  = m0 + lrow * 4 + r;
            int bb  = gg >> 9;
            int pos = gg & (L_ - 1);
            float v0 = (bacc0[r] + b2a) * 0.5f;
            float v1 = (bacc1[r] + b2b) * 0.5f;
            int o0 = lcol, o1 = 16 + lcol;
            if (o0 & 1) ws[BQ_OFF + ((size_t)bb * NL + (o0 >> 1)) * L_ + pos] = v0;
            else        ws[BK_OFF + ((size_t)bb * NL + (o0 >> 1)) * L_ + pos] = v0;
            if (o1 & 1) ws[BQ_OFF + ((size_t)bb * NL + (o1 >> 1)) * L_ + pos] = v1;
            else        ws[BK_OFF + ((size_t)bb * NL + (o1 >> 1)) * L_ + pos] = v1;
        }
    }
}

// --------------------------------------------------------------------------
// K3 (fused): qk 64x64 tile in registers -> +bias/masks -> 16 l stores.
__global__ __launch_bounds__(256) void qk_bcast_kernel(
    const int* __restrict__ am, const float* __restrict__ ws, float* __restrict__ out)
{
    __shared__ float Qs[64][68];
    __shared__ float Ks[64][68];
    __shared__ float BQs[16][64];
    __shared__ float BKs[16][64];
    __shared__ float maskM[64];
    __shared__ float maskN[64];

    const int tid = threadIdx.x;
    const int bid = blockIdx.x;
    const int bb = bid >> 6;
    const int mt = (bid >> 3) & 7;
    const int nt = bid & 7;
    const int m0 = mt * 64, n0 = nt * 64;

    // stage Q/K transposed
    {
        int r0   = tid >> 4;
        int dcol = (tid & 15) * 4;
        #pragma unroll
        for (int rr = 0; rr < 4; rr++) {
            int r = r0 + rr * 16;
            float4 q = *(const float4*)&ws[QROT_OFF + ((size_t)(bb * L_ + m0 + r)) * HEAD + dcol];
            float4 k = *(const float4*)&ws[KROT_OFF + ((size_t)(bb * L_ + n0 + r)) * HEAD + dcol];
            Qs[dcol + 0][r] = q.x; Qs[dcol + 1][r] = q.y;
            Qs[dcol + 2][r] = q.z; Qs[dcol + 3][r] = q.w;
            Ks[dcol + 0][r] = k.x; Ks[dcol + 1][r] = k.y;
            Ks[dcol + 2][r] = k.z; Ks[dcol + 3][r] = k.w;
        }
    }
    // stage BQ/BK tiles: 16 l x 64
    {
        int l = tid >> 4;
        int c = (tid & 15) * 4;
        *(float4*)&BQs[l][c] = *(const float4*)&ws[BQ_OFF + ((size_t)bb * NL + l) * L_ + m0 + c];
        *(float4*)&BKs[l][c] = *(const float4*)&ws[BK_OFF + ((size_t)bb * NL + l) * L_ + n0 + c];
    }
    if (tid < 64)       maskM[tid]      = (float)am[bb * L_ + m0 + tid];
    else if (tid < 128) maskN[tid - 64] = (float)am[bb * L_ + n0 + (tid - 64)];
    __syncthreads();

    const int ty = tid >> 4;
    const int tx = tid & 15;
    float acc[4][4] = {};
    #pragma unroll 8
    for (int d = 0; d < HEAD; d++) {
        float4 a  = *(const float4*)&Qs[d][ty * 4];
        float4 bv = *(const float4*)&Ks[d][tx * 4];
        acc[0][0] += a.x * bv.x; acc[0][1] += a.x * bv.y; acc[0][2] += a.x * bv.z; acc[0][3] += a.x * bv.w;
        acc[1][0] += a.y * bv.x; acc[1][1] += a.y * bv.y; acc[1][2] += a.y * bv.z; acc[1][3] += a.y * bv.w;
        acc[2][0] += a.z * bv.x; acc[2][1] += a.z * bv.y; acc[2][2] += a.z * bv.z; acc[2][3] += a.z * bv.w;
        acc[3][0] += a.w * bv.x; acc[3][1] += a.w * bv.y; acc[3][2] += a.w * bv.z; acc[3][3] += a.w * bv.w;
    }

    // base = qk*0.125 - attn_mask*INF - tril*INF
    float4 base[4];
    #pragma unroll
    for (int r = 0; r < 4; r++) {
        int m = m0 + ty * 4 + r;
        float mm = maskM[ty * 4 + r];
        #pragma unroll
        for (int c = 0; c < 4; c++) {
            int n = n0 + tx * 4 + c;
            float v = acc[r][c] * 0.125f
                    - (1.0f - mm * maskN[tx * 4 + c]) * INF_
                    - ((n < m) ? INF_ : 0.0f);
            ((float*)&base[r])[c] = v;
        }
    }

    // output: 16 l-channels x 4 rows x float4
    #pragma unroll
    for (int l = 0; l < NL; l++) {
        float4 bk4 = *(const float4*)&BKs[l][tx * 4];
        size_t outb = (((size_t)(bb * NL + l)) * L_ + m0 + ty * 4) * L_ + n0 + tx * 4;
        #pragma unroll
        for (int r = 0; r < 4; r++) {
            float bq = BQs[l][ty * 4 + r];
            float4 o;
            o.x = base[r].x + bk4.x + bq;
            o.y = base[r].y + bk4.y + bq;
            o.z = base[r].z + bk4.z + bq;
            o.w = base[r].w + bk4.w + bq;
            *(float4*)&out[outb + (size_t)r * L_] = o;
        }
    }
}

// --------------------------------------------------------------------------
extern "C" void kernel_launch(void* const* d_in, const int* in_sizes, int n_in,
                              void* d_out, int out_size, void* d_ws, size_t ws_size,
                              hipStream_t stream) {
    const float* X  = (const float*)d_in[0];
    const int*   am = (const int*)d_in[1];
    const float* W1 = (const float*)d_in[2];
    const float* b1 = (const float*)d_in[3];
    const float* W2 = (const float*)d_in[4];
    const float* b2 = (const float*)d_in[5];
    float* out = (float*)d_out;
    float* ws  = (float*)d_ws;

    prep_kernel<<<81, 256, 0, stream>>>(W1, W2, ws);
    gemm1_fused_kernel<<<(B_ * L_) / 16, 1024, 0, stream>>>(X, b1, b2, ws);
    qk_bcast_kernel<<<B_ * (L_ / 64) * (L_ / 64), 256, 0, stream>>>(am, ws, out);
}